// Round 4
// baseline (255.287 us; speedup 1.0000x reference)
//
#include <hip/hip_runtime.h>
#include <hip/hip_cooperative_groups.h>
#include <math.h>

// node1 [N,1,128] f32, node2 [N,32,128] f32, N=50000.
// logit[n] = dot(node1[n], sum_m node2[n,m,:]); out = softmax(logit over n).
//
// Single cooperative kernel: each wave computes NPW logits (kept in LDS),
// accumulates exp((double)logit) partials (double is overflow-safe: logits
// ~N(0,64^2), max ~300 << 709), grid.sync(), every block redundantly reduces
// the ~962 block partials (8 KB, L2), then writes its 52 contiguous outputs.
// Fallback to the proven 3-kernel path if cooperative launch is unavailable.

typedef float f32x4 __attribute__((ext_vector_type(4)));

namespace cg = cooperative_groups;

#define D4   32     // 128 floats = 32 float4 per node1 row
#define N2F4 1024   // 32*128 floats = 1024 float4 per node2 slab
#define NPW  13     // nodes per wave
#define WPB  4      // waves per block
#define NPB  (NPW * WPB)   // 52 nodes per block

// ==================== fused cooperative kernel ====================
__global__ __launch_bounds__(256, 4) void fused_kernel(
    const f32x4* __restrict__ n1,
    const f32x4* __restrict__ n2,
    float* __restrict__ out,
    double* __restrict__ psum,
    int N, int nblocks)
{
    __shared__ float  slog[NPB];
    __shared__ double se[WPB];
    __shared__ double sred[WPB];
    __shared__ float  sbcast;

    const int tid  = threadIdx.x;
    const int wave = tid >> 6;
    const int lane = tid & 63;
    const int base = (blockIdx.x * WPB + wave) * NPW;  // first node of this wave

    double esum = 0.0;
#pragma unroll
    for (int k = 0; k < NPW; ++k) {
        const int n = base + k;
        if (n < N) {
            const f32x4* __restrict__ a = n1 + (size_t)n * D4;
            const f32x4* __restrict__ b = n2 + (size_t)n * N2F4;
            const f32x4 av = a[lane & 31];
            float acc = 0.0f;
#pragma unroll
            for (int i = 0; i < 16; ++i) {
                const f32x4 bv = __builtin_nontemporal_load(&b[lane + i * 64]);
                acc += av.x * bv.x + av.y * bv.y + av.z * bv.z + av.w * bv.w;
            }
#pragma unroll
            for (int off = 32; off > 0; off >>= 1)
                acc += __shfl_down(acc, off);
            if (lane == 0) {
                slog[wave * NPW + k] = acc;
                esum += exp((double)acc);
            }
        }
    }
    if (lane == 0) se[wave] = esum;
    __syncthreads();
    if (tid == 0)
        psum[blockIdx.x] = (se[0] + se[1]) + (se[2] + se[3]);

    cg::this_grid().sync();

    // every block redundantly reduces the nblocks (~962) doubles from L2
    double s = 0.0;
    for (int i = tid; i < nblocks; i += 256) s += psum[i];
#pragma unroll
    for (int off = 32; off > 0; off >>= 1) s += __shfl_down(s, off);
    if (lane == 0) sred[wave] = s;
    __syncthreads();
    if (tid == 0) {
        double tot = (sred[0] + sred[1]) + (sred[2] + sred[3]);
        sbcast = (float)log(tot);
    }
    __syncthreads();
    const float logS = sbcast;

    // write this block's 52 contiguous outputs
    const int bbase = blockIdx.x * NPB;
    if (tid < NPB && bbase + tid < N)
        out[bbase + tid] = expf(slog[tid] - logS);
}

// ==================== fallback path (proven R1 kernels) ====================
__global__ __launch_bounds__(256) void logits_kernel(
    const f32x4* __restrict__ n1, const f32x4* __restrict__ n2,
    float* __restrict__ logits, double* __restrict__ psum, int N)
{
    __shared__ double se[4];
    const int wave = threadIdx.x >> 6;
    const int lane = threadIdx.x & 63;
    const int n = blockIdx.x * 4 + wave;

    double e = 0.0;
    if (n < N) {
        const f32x4* __restrict__ a = n1 + (size_t)n * D4;
        const f32x4* __restrict__ b = n2 + (size_t)n * N2F4;
        const f32x4 av = a[lane & 31];
        float acc = 0.0f;
#pragma unroll
        for (int i = 0; i < 16; ++i) {
            const f32x4 bv = __builtin_nontemporal_load(&b[lane + i * 64]);
            acc += av.x * bv.x + av.y * bv.y + av.z * bv.z + av.w * bv.w;
        }
#pragma unroll
        for (int off = 32; off > 0; off >>= 1)
            acc += __shfl_down(acc, off);
        if (lane == 0) {
            logits[n] = acc;
            e = exp((double)acc);
        }
    }
    if (lane == 0) se[wave] = e;
    __syncthreads();
    if (threadIdx.x == 0)
        psum[blockIdx.x] = (se[0] + se[1]) + (se[2] + se[3]);
}

__global__ __launch_bounds__(1024) void combine_kernel(
    const double* __restrict__ psum, double* __restrict__ stats, int nb)
{
    __shared__ double sred[16];
    const int tid  = threadIdx.x;
    const int lane = tid & 63;
    const int wid  = tid >> 6;

    double s = 0.0;
    for (int i = tid; i < nb; i += 1024) s += psum[i];
#pragma unroll
    for (int off = 32; off > 0; off >>= 1) s += __shfl_down(s, off);
    if (lane == 0) sred[wid] = s;
    __syncthreads();
    if (tid == 0) {
        double tot = 0.0;
        for (int i = 0; i < 16; ++i) tot += sred[i];
        stats[0] = log(tot);
    }
}

__global__ __launch_bounds__(256) void scale_kernel(
    const float* __restrict__ logits, const double* __restrict__ stats,
    float* __restrict__ out, int N)
{
    const float logS = (float)stats[0];
    for (int i = blockIdx.x * 256 + threadIdx.x; i < N; i += gridDim.x * 256)
        out[i] = expf(logits[i] - logS);
}

// ==================== launcher ====================
extern "C" void kernel_launch(void* const* d_in, const int* in_sizes, int n_in,
                              void* d_out, int out_size, void* d_ws, size_t ws_size,
                              hipStream_t stream)
{
    const f32x4* n1 = (const f32x4*)d_in[0];
    const f32x4* n2 = (const f32x4*)d_in[1];
    float* out = (float*)d_out;
    const int N = out_size;                    // 50000

    // ws layout: logits (N f32, fallback only) | psum (up to 12500 f64) | stats (1 f64)
    float*  logits = (float*)d_ws;
    char*   base   = (char*)d_ws;
    size_t  off    = ((size_t)N * sizeof(float) + 7) & ~(size_t)7;
    double* psum   = (double*)(base + off);
    double* stats  = (double*)(base + off + (size_t)12500 * sizeof(double));

    // cooperative single-kernel path
    const int nwaves  = (N + NPW - 1) / NPW;           // 3847
    int       nblocks = (nwaves + WPB - 1) / WPB;      // 962 (co-resident at 4/CU)

    void* args[] = { (void*)&n1, (void*)&n2, (void*)&out, (void*)&psum,
                     (void*)&N, (void*)&nblocks };
    hipError_t err = hipLaunchCooperativeKernel(
        (const void*)fused_kernel, dim3(nblocks), dim3(256), args, 0, stream);

    if (err != hipSuccess) {
        // fallback: proven 3-kernel path
        (void)hipGetLastError();               // clear sticky error
        const int blocks1 = (N + 3) / 4;       // 12500
        logits_kernel<<<blocks1, 256, 0, stream>>>(n1, n2, logits, psum, N);
        combine_kernel<<<1, 1024, 0, stream>>>(psum, stats, blocks1);
        const int blocks3 = (N + 255) / 256;
        scale_kernel<<<blocks3, 256, 0, stream>>>(logits, stats, out, N);
    }
}